// Round 5
// baseline (147.020 us; speedup 1.0000x reference)
//
#include <hip/hip_runtime.h>
#include <hip/hip_fp16.h>

// B=8, T=S=512, M=N=512, H=128
// score[b,t,s] = (1/sqrt(512)) * sum_h v[h]*tanh(x1[b,t,h]+x2[b,s,h])
// tanh(x) = 1 - 2/(1+e^{2x}) => score = (Sv - 2*sum_h v_h*sigma_h)/SCALE,
//   sigma = 1/(1+e), e = exp2(z1+z2), z_i = 2*log2(e)*x_i (z stored f32).
// Round-5: r3's exp2 score math (best measured: 60.6 vs 64.5/64.7 for packed
// variants), split into two s-half dispatches (~31 us each) so proj_kernel
// finally surfaces in rocprof top-5 with real counters. Proj writes plain z
// f32 planes (cheapest epilogue of any variant; no combine kernel).
// 4-way rcp merge: v1/a1+..+v4/a4 = num/(a1a2a3a4), one rcp per 4 elements.

constexpr float SCALE_IN  = 2.8853900817779268f;   // 2*log2(e)
constexpr float INV_SCALE = 0.04419417382415922f;  // 1/sqrt(512)

// ---------------- Projection GEMM -> z planes --------------------------------
// Fused full-K (round-0 structure): grid 256 blocks (128 per matrix),
// 512 threads. Block: 32 rows x 128 h. LDS: A 32x64 (8KB) + W 64x128 (32KB).
// Thread: 2 rows x 4 h. Epilogue: z = acc * 2log2e, plain f32 store.
__global__ __launch_bounds__(512) void proj_kernel(
    const float* __restrict__ q,  const float* __restrict__ w2,
    const float* __restrict__ ky, const float* __restrict__ w1,
    float* __restrict__ x1z, float* __restrict__ x2z) {
  __shared__ float As[32 * 64];    // [row][k]
  __shared__ float Ws[64 * 128];   // [k][h]

  int blk = blockIdx.x;
  const float* A; const float* W; float* O;
  if (blk < 128) { A = q;  W = w2; O = x1z; }
  else           { blk -= 128; A = ky; W = w1; O = x2z; }
  const int rbase = blk * 32;
  const int tid = threadIdx.x;

  const int rq = tid >> 5;          // 0..15 -> rows 2*rq+{0,1}
  const int hq = tid & 31;          // h = 4*hq+{0..3}

  float acc[2][4];
#pragma unroll
  for (int r = 0; r < 2; ++r)
#pragma unroll
    for (int c = 0; c < 4; ++c) acc[r][c] = 0.0f;

  for (int kb = 0; kb < 512; kb += 64) {
    // stage A: 2048 floats, 1 float4/thread (coalesced 16-lane rows)
    {
      const int arow = tid >> 4;          // 0..31
      const int kq4  = (tid & 15) * 4;
      *(float4*)(As + arow * 64 + kq4) =
          *(const float4*)(A + (size_t)(rbase + arow) * 512 + kb + kq4);
      // stage W: 8192 floats, 4 float4/thread (coalesced 32-lane rows)
      const int wrow = tid >> 5;          // 0..15
      const int hq4  = (tid & 31) * 4;
#pragma unroll
      for (int p = 0; p < 4; ++p)
        *(float4*)(Ws + (wrow + 16 * p) * 128 + hq4) =
            *(const float4*)(W + (size_t)(kb + wrow + 16 * p) * 128 + hq4);
    }
    __syncthreads();
#pragma unroll 4
    for (int k4 = 0; k4 < 64; k4 += 4) {
      float a[2][4], w[4][4];
      *(float4*)a[0] = *(const float4*)(As + (2 * rq + 0) * 64 + k4);
      *(float4*)a[1] = *(const float4*)(As + (2 * rq + 1) * 64 + k4);
#pragma unroll
      for (int kk = 0; kk < 4; ++kk)
        *(float4*)w[kk] = *(const float4*)(Ws + (k4 + kk) * 128 + 4 * hq);
#pragma unroll
      for (int kk = 0; kk < 4; ++kk)
#pragma unroll
        for (int r = 0; r < 2; ++r)
#pragma unroll
          for (int c = 0; c < 4; ++c)
            acc[r][c] = fmaf(a[r][kk], w[kk][c], acc[r][c]);
    }
    __syncthreads();
  }

#pragma unroll
  for (int r = 0; r < 2; ++r) {
    float4 z;
    z.x = acc[r][0] * SCALE_IN;
    z.y = acc[r][1] * SCALE_IN;
    z.z = acc[r][2] * SCALE_IN;
    z.w = acc[r][3] * SCALE_IN;
    *(float4*)(O + (size_t)(rbase + 2 * rq + r) * 128 + 4 * hq) = z;
  }
}

// ---------------- Score (one s-half per dispatch) ----------------------------
// 512 blocks x 512 threads per half. Tile 64(t) x 32(s), H in two 64-h
// phases. LDS 24KB ([64h][64t] + [64h][32s] f32) -> 2 blocks/CU resident
// (r1-verified geometry). Thread: 2 t x 2 s.
// Per element: v_add + v_min + v_exp_f32 + v_add, then 4-way rcp merge.
__global__ __launch_bounds__(512) void score_half_kernel(
    const float* __restrict__ x1z, const float* __restrict__ x2z,
    const float* __restrict__ v, float* __restrict__ out, int shalf) {
  __shared__ float x1l[64 * 64];  // [h(64)][t(64)] 16KB
  __shared__ float x2l[64 * 32];  // [h(64)][s(32)]  8KB

  const int tid   = threadIdx.x;
  const int b     = blockIdx.x >> 6;
  const int tile  = blockIdx.x & 63;
  const int tbase = (tile >> 3) * 64;                 // 8 t-tiles
  const int sbase = shalf * 256 + (tile & 7) * 32;    // 8 s-tiles per half

  const float* x1g = x1z + (size_t)(b * 512 + tbase) * 128;
  const float* x2g = x2z + (size_t)(b * 512 + sbase) * 128;

  const int sg = tid & 15;   // s = 2*sg+j
  const int tg = tid >> 4;   // 0..31, t = 2*tg+i

  float racc[2][2] = {{0.0f, 0.0f}, {0.0f, 0.0f}};
  float sv = 0.0f;

  for (int ph = 0; ph < 2; ++ph) {
    // transposed staging: [row][h] global -> [h][row] LDS.
    {
      const int r1 = tid & 63;            // t-row
      const int c0 = tid >> 6;            // 0..7
#pragma unroll
      for (int p = 0; p < 2; ++p) {
        const int c = c0 + 8 * p;         // 0..15 -> h = 4c..4c+3
        const float4 a =
            *(const float4*)(x1g + (size_t)r1 * 128 + ph * 64 + 4 * c);
        x1l[(4 * c + 0) * 64 + r1] = a.x;
        x1l[(4 * c + 1) * 64 + r1] = a.y;
        x1l[(4 * c + 2) * 64 + r1] = a.z;
        x1l[(4 * c + 3) * 64 + r1] = a.w;
      }
      const int r2 = tid & 31;            // s-row
      const int c2 = tid >> 5;            // 0..15
      const float4 s =
          *(const float4*)(x2g + (size_t)r2 * 128 + ph * 64 + 4 * c2);
      x2l[(4 * c2 + 0) * 32 + r2] = s.x;
      x2l[(4 * c2 + 1) * 32 + r2] = s.y;
      x2l[(4 * c2 + 2) * 32 + r2] = s.z;
      x2l[(4 * c2 + 3) * 32 + r2] = s.w;
    }
    __syncthreads();

    for (int hg = 0; hg < 16; ++hg) {
      const int h0 = hg * 4;
      const float4 vq = *(const float4*)(v + ph * 64 + h0);  // uniform s_load
      sv += (vq.x + vq.y) + (vq.z + vq.w);

      float zt[2][4];   // [i][qq]
      float zs[2][4];   // [j][qq]
#pragma unroll
      for (int qq = 0; qq < 4; ++qq) {
        const float2 tp = *(const float2*)(x1l + (h0 + qq) * 64 + 2 * tg);
        zt[0][qq] = tp.x;
        zt[1][qq] = tp.y;
        const float2 sp = *(const float2*)(x2l + (h0 + qq) * 32 + 2 * sg);
        zs[0][qq] = sp.x;
        zs[1][qq] = sp.y;
      }

#pragma unroll
      for (int i = 0; i < 2; ++i) {
#pragma unroll
        for (int j = 0; j < 2; ++j) {
          float e[4];
#pragma unroll
          for (int qq = 0; qq < 4; ++qq) {
            const float z = fminf(zt[i][qq] + zs[j][qq], 30.0f);
            e[qq] = __builtin_amdgcn_exp2f(z);   // e <= 2^30; underflow -> 0
          }
          const float a0 = e[0] + 1.0f, a1 = e[1] + 1.0f;
          const float a2 = e[2] + 1.0f, a3 = e[3] + 1.0f;
          const float p12 = a0 * a1, p34 = a2 * a3;  // den <= 2^120, no inf
          float u1 = vq.x * a1; u1 = fmaf(vq.y, a0, u1);
          float u2 = vq.z * a3; u2 = fmaf(vq.w, a2, u2);
          float num = u1 * p34; num = fmaf(u2, p12, num);
          const float den = p12 * p34;
          racc[i][j] = fmaf(num, __builtin_amdgcn_rcpf(den), racc[i][j]);
        }
      }
    }
    __syncthreads();   // before next phase overwrites LDS
  }

  const float c1v = sv * INV_SCALE;
  const float c2v = -2.0f * INV_SCALE;
#pragma unroll
  for (int i = 0; i < 2; ++i) {
    const int t = tbase + 2 * tg + i;
    float2 o;
    o.x = fmaf(racc[i][0], c2v, c1v);
    o.y = fmaf(racc[i][1], c2v, c1v);
    *(float2*)(out + (size_t)(b * 512 + t) * 512 + sbase + 2 * sg) = o;
  }
}

extern "C" void kernel_launch(void* const* d_in, const int* in_sizes, int n_in,
                              void* d_out, int out_size, void* d_ws, size_t ws_size,
                              hipStream_t stream) {
  const float* query = (const float*)d_in[0];  // (8,512,512)
  const float* keys  = (const float*)d_in[1];  // (8,512,512)
  const float* W1    = (const float*)d_in[2];  // (512,128) pairs with keys
  const float* W2    = (const float*)d_in[3];  // (512,128) pairs with query
  const float* v     = (const float*)d_in[4];  // (128,)
  float* out = (float*)d_out;                  // (8,512,512) fp32

  float* x1zp = (float*)d_ws;                  // 8*512*128 f32 (2 MB)
  float* x2zp = x1zp + 8 * 512 * 128;          // 2 MB more

  hipLaunchKernelGGL(proj_kernel, dim3(256), dim3(512), 0, stream,
                     query, W2, keys, W1, x1zp, x2zp);
  hipLaunchKernelGGL(score_half_kernel, dim3(512), dim3(512), 0, stream,
                     x1zp, x2zp, v, out, 0);
  hipLaunchKernelGGL(score_half_kernel, dim3(512), dim3(512), 0, stream,
                     x1zp, x2zp, v, out, 1);
}

// Round 7
// 140.297 us; speedup vs baseline: 1.0479x; 1.0479x over previous
//
#include <hip/hip_runtime.h>
#include <hip/hip_fp16.h>

// B=8, T=S=512, M=N=512, H=128
// score[b,t,s] = (1/sqrt(512)) * sum_h v[h]*tanh(x1[b,t,h]+x2[b,s,h])
// tanh(x) = 1 - 2/(1+e^{2x}) => score = (Sv - 2*sum_h v_h*sigma_h)/SCALE,
//   sigma = 1/(1+e), e = exp2(z1+z2), z_i = 2*log2(e)*x_i (z stored f32).
// Round-7: recovery from failed cooperative fusion (r6). Two launches:
// r5's fused proj (z f32 planes, verified) + r3's score geometry (best
// measured 60.6us), with the score inner merge rewritten over s-pairs as
// float2 ext-vectors. Element-wise identical arithmetic; if the backend
// selects gfx950 VOP3P packed-fp32 (v_pk_add/mul/fma_f32) the non-trans
// VALU work halves; if it scalarizes we get exactly r3's instructions.
// 4-way rcp merge: v1/a1+..+v4/a4 = num/(a1a2a3a4), one rcp per 4 elements.

constexpr float SCALE_IN  = 2.8853900817779268f;   // 2*log2(e)
constexpr float INV_SCALE = 0.04419417382415922f;  // 1/sqrt(512)

typedef float v2f __attribute__((ext_vector_type(2)));

__device__ __forceinline__ v2f exp2v(v2f z) {
  v2f r;
  r.x = __builtin_amdgcn_exp2f(z.x);
  r.y = __builtin_amdgcn_exp2f(z.y);
  return r;
}
__device__ __forceinline__ v2f rcpv(v2f d) {
  v2f r;
  r.x = __builtin_amdgcn_rcpf(d.x);
  r.y = __builtin_amdgcn_rcpf(d.y);
  return r;
}

// ---------------- Projection GEMM -> z planes (r5-verified) ------------------
// Fused full-K: grid 256 blocks (128 per matrix), 512 threads. Block:
// 32 rows x 128 h. LDS: A 32x64 (8KB) + W 64x128 (32KB). Thread: 2r x 4h.
// Epilogue: z = acc * 2log2e, plain f32 store.
__global__ __launch_bounds__(512) void proj_kernel(
    const float* __restrict__ q,  const float* __restrict__ w2,
    const float* __restrict__ ky, const float* __restrict__ w1,
    float* __restrict__ x1z, float* __restrict__ x2z) {
  __shared__ float As[32 * 64];    // [row][k]
  __shared__ float Ws[64 * 128];   // [k][h]

  int blk = blockIdx.x;
  const float* A; const float* W; float* O;
  if (blk < 128) { A = q;  W = w2; O = x1z; }
  else           { blk -= 128; A = ky; W = w1; O = x2z; }
  const int rbase = blk * 32;
  const int tid = threadIdx.x;

  const int rq = tid >> 5;          // 0..15 -> rows 2*rq+{0,1}
  const int hq = tid & 31;          // h = 4*hq+{0..3}

  float acc[2][4];
#pragma unroll
  for (int r = 0; r < 2; ++r)
#pragma unroll
    for (int c = 0; c < 4; ++c) acc[r][c] = 0.0f;

  for (int kb = 0; kb < 512; kb += 64) {
    {
      const int arow = tid >> 4;          // 0..31
      const int kq4  = (tid & 15) * 4;
      *(float4*)(As + arow * 64 + kq4) =
          *(const float4*)(A + (size_t)(rbase + arow) * 512 + kb + kq4);
      const int wrow = tid >> 5;          // 0..15
      const int hq4  = (tid & 31) * 4;
#pragma unroll
      for (int p = 0; p < 4; ++p)
        *(float4*)(Ws + (wrow + 16 * p) * 128 + hq4) =
            *(const float4*)(W + (size_t)(kb + wrow + 16 * p) * 128 + hq4);
    }
    __syncthreads();
#pragma unroll 4
    for (int k4 = 0; k4 < 64; k4 += 4) {
      float a[2][4], w[4][4];
      *(float4*)a[0] = *(const float4*)(As + (2 * rq + 0) * 64 + k4);
      *(float4*)a[1] = *(const float4*)(As + (2 * rq + 1) * 64 + k4);
#pragma unroll
      for (int kk = 0; kk < 4; ++kk)
        *(float4*)w[kk] = *(const float4*)(Ws + (k4 + kk) * 128 + 4 * hq);
#pragma unroll
      for (int kk = 0; kk < 4; ++kk)
#pragma unroll
        for (int r = 0; r < 2; ++r)
#pragma unroll
          for (int c = 0; c < 4; ++c)
            acc[r][c] = fmaf(a[r][kk], w[kk][c], acc[r][c]);
    }
    __syncthreads();
  }

#pragma unroll
  for (int r = 0; r < 2; ++r) {
    float4 z;
    z.x = acc[r][0] * SCALE_IN;
    z.y = acc[r][1] * SCALE_IN;
    z.z = acc[r][2] * SCALE_IN;
    z.w = acc[r][3] * SCALE_IN;
    *(float4*)(O + (size_t)(rbase + 2 * rq + r) * 128 + 4 * hq) = z;
  }
}

// ---------------- Main score kernel (r3 geometry, v2f inner) -----------------
// 512 blocks x 512 threads. Tile 64(t) x 64(s), H in two 64-h phases.
// LDS 32KB ([64h][64t] + [64h][64s] f32). Thread: 2 t x 4 s = 2t x 2 s-pairs.
// Per elem: pk_add + pk_min + exp2 + pk_add1, then pk 4-way rcp merge.
__global__ __launch_bounds__(512, 4) void score_kernel(
    const float* __restrict__ x1z, const float* __restrict__ x2z,
    const float* __restrict__ v, float* __restrict__ out) {
  __shared__ float x1l[64 * 64];  // [h(64)][t(64)] 16KB
  __shared__ float x2l[64 * 64];  // [h(64)][s(64)] 16KB

  const int tid   = threadIdx.x;
  const int b     = blockIdx.x >> 6;
  const int tile  = blockIdx.x & 63;
  const int tbase = (tile >> 3) * 64;    // 8 t-tiles
  const int sbase = (tile & 7) * 64;     // 8 s-tiles

  const float* x1g = x1z + (size_t)(b * 512 + tbase) * 128;
  const float* x2g = x2z + (size_t)(b * 512 + sbase) * 128;

  const int sg = tid & 15;   // s = 4*sg+j (coalesced float4 stores)
  const int tg = tid >> 4;   // 0..31, t = 2*tg+i

  v2f racc[2][2];
#pragma unroll
  for (int i = 0; i < 2; ++i)
#pragma unroll
    for (int jp = 0; jp < 2; ++jp) racc[i][jp] = (v2f){0.0f, 0.0f};
  float sv = 0.0f;

  const v2f C30 = {30.0f, 30.0f};

  for (int ph = 0; ph < 2; ++ph) {
    // transposed staging: [row][h] global -> [h][row] LDS. 2-way banks, free.
    {
      const int r1 = tid & 63;            // row within tile
      const int c0 = tid >> 6;            // 0..7
#pragma unroll
      for (int p = 0; p < 2; ++p) {
        const int c = c0 + 8 * p;         // 0..15 -> h = 4c..4c+3
        const float4 a =
            *(const float4*)(x1g + (size_t)r1 * 128 + ph * 64 + 4 * c);
        x1l[(4 * c + 0) * 64 + r1] = a.x;
        x1l[(4 * c + 1) * 64 + r1] = a.y;
        x1l[(4 * c + 2) * 64 + r1] = a.z;
        x1l[(4 * c + 3) * 64 + r1] = a.w;
        const float4 s =
            *(const float4*)(x2g + (size_t)r1 * 128 + ph * 64 + 4 * c);
        x2l[(4 * c + 0) * 64 + r1] = s.x;
        x2l[(4 * c + 1) * 64 + r1] = s.y;
        x2l[(4 * c + 2) * 64 + r1] = s.z;
        x2l[(4 * c + 3) * 64 + r1] = s.w;
      }
    }
    __syncthreads();

    for (int hg = 0; hg < 16; ++hg) {
      const int h0 = hg * 4;
      const float4 vq = *(const float4*)(v + ph * 64 + h0);  // uniform s_load
      sv += (vq.x + vq.y) + (vq.z + vq.w);

      float zt[2][4];    // [i][qq]
      v2f   zs[2][4];    // [jp][qq], s-pair packed
#pragma unroll
      for (int qq = 0; qq < 4; ++qq) {
        const float2 tp = *(const float2*)(x1l + (h0 + qq) * 64 + 2 * tg);
        zt[0][qq] = tp.x;
        zt[1][qq] = tp.y;
        const float4 sp = *(const float4*)(x2l + (h0 + qq) * 64 + 4 * sg);
        zs[0][qq] = (v2f){sp.x, sp.y};
        zs[1][qq] = (v2f){sp.z, sp.w};
      }

#pragma unroll
      for (int i = 0; i < 2; ++i) {
#pragma unroll
        for (int jp = 0; jp < 2; ++jp) {
          const v2f e0 =
              exp2v(__builtin_elementwise_min(zt[i][0] + zs[jp][0], C30));
          const v2f e1 =
              exp2v(__builtin_elementwise_min(zt[i][1] + zs[jp][1], C30));
          const v2f e2 =
              exp2v(__builtin_elementwise_min(zt[i][2] + zs[jp][2], C30));
          const v2f e3 =
              exp2v(__builtin_elementwise_min(zt[i][3] + zs[jp][3], C30));
          const v2f A0 = e0 + 1.0f, A1 = e1 + 1.0f;
          const v2f A2 = e2 + 1.0f, A3 = e3 + 1.0f;
          const v2f P12 = A0 * A1, P34 = A2 * A3;   // den <= 2^120, no inf
          const v2f U1 = vq.x * A1 + vq.y * A0;
          const v2f U2 = vq.z * A3 + vq.w * A2;
          const v2f NUM = U1 * P34 + U2 * P12;
          const v2f DEN = P12 * P34;
          racc[i][jp] += NUM * rcpv(DEN);
        }
      }
    }
    __syncthreads();   // before next phase overwrites LDS
  }

  const float c1v = sv * INV_SCALE;
  const float c2v = -2.0f * INV_SCALE;
#pragma unroll
  for (int i = 0; i < 2; ++i) {
    const int t = tbase + 2 * tg + i;
    float4 o;
    o.x = fmaf(racc[i][0].x, c2v, c1v);
    o.y = fmaf(racc[i][0].y, c2v, c1v);
    o.z = fmaf(racc[i][1].x, c2v, c1v);
    o.w = fmaf(racc[i][1].y, c2v, c1v);
    *(float4*)(out + (size_t)(b * 512 + t) * 512 + sbase + 4 * sg) = o;
  }
}

extern "C" void kernel_launch(void* const* d_in, const int* in_sizes, int n_in,
                              void* d_out, int out_size, void* d_ws, size_t ws_size,
                              hipStream_t stream) {
  const float* query = (const float*)d_in[0];  // (8,512,512)
  const float* keys  = (const float*)d_in[1];  // (8,512,512)
  const float* W1    = (const float*)d_in[2];  // (512,128) pairs with keys
  const float* W2    = (const float*)d_in[3];  // (512,128) pairs with query
  const float* v     = (const float*)d_in[4];  // (128,)
  float* out = (float*)d_out;                  // (8,512,512) fp32

  float* x1zp = (float*)d_ws;                  // 8*512*128 f32 (2 MB)
  float* x2zp = x1zp + 8 * 512 * 128;          // 2 MB more

  hipLaunchKernelGGL(proj_kernel, dim3(256), dim3(512), 0, stream,
                     query, W2, keys, W1, x1zp, x2zp);
  hipLaunchKernelGGL(score_kernel, dim3(512), dim3(512), 0, stream,
                     x1zp, x2zp, v, out);
}